// Round 6
// baseline (233.180 us; speedup 1.0000x reference)
//
#include <hip/hip_runtime.h>
#include <math.h>

// TopKRouter: x[16384,2048] fp32, W[64,2048] fp32
// out: [0..32767] top2 indices (as float), [32768..65535] gates, [65536] aux
// Split-fp16 MFMA (3-term: xh*wh + xh*wl + xl*wh).
// R6: coarse-chunk LDS pipeline. R2/R3/R5 all shared: fine chunks (256B/row
// scattered reads) + a sync every ~500cyc -> ~6300cyc/chunk exposed latency.
// Fix: K-chunk 256 floats (8 chunks), stage-to-use = full chunk (~2600cyc >
// 900cyc HBM latency) so plain __syncthreads dbuf hides everything; each
// global_load_lds stages 1KB CONTIGUOUS of one row per wave (fat streams);
// XOR-swizzled source (linear LDS dest, m173) -> 2-way-free bank reads;
// TM=16 / 1024 blocks / 4 blocks/CU = 16 waves/CU (R2's best-measured shape).
// W: direct L2-resident frag-linear loads per step (unrolled body + TLP).
#define NTOK 16384
#define DDIM 2048
#define NEXP 64
#define TM   16                 // tokens per block (1 MFMA M-tile)
#define NBLK (NTOK / TM)        // 1024 blocks -> 4 blocks/CU
#define KCH  256                // K floats per chunk per row (1 KB)
#define NCH  (DDIM / KCH)       // 8 chunks
#define SPC  (KCH / 32)         // 8 K32 steps per chunk

typedef _Float16 half8v __attribute__((ext_vector_type(8)));
typedef float    f32x4  __attribute__((ext_vector_type(4)));

#define MFMA16(a, b, c) __builtin_amdgcn_mfma_f32_16x16x32_f16((a), (b), (c), 0, 0, 0)

__device__ __forceinline__ void stage16(const void* g, void* l) {
    __builtin_amdgcn_global_load_lds(
        (const __attribute__((address_space(1))) unsigned int*)g,
        (__attribute__((address_space(3))) unsigned int*)l, 16, 0, 0);
}

// W prep: fp32 -> (wh, wl) fp16 in MFMA-B fragment-linear layout (r5-verified):
// element (e,k): S=k>>5, nb=e>>4, nl=e&15, q=(k>>3)&3, j=k&7
// off = S*2048 + nb*512 + q*128 + nl*8 + j
__global__ __launch_bounds__(256) void prep_kernel(const float* __restrict__ W,
                                                   _Float16* __restrict__ Wh,
                                                   _Float16* __restrict__ Wl,
                                                   float* __restrict__ accg) {
    int idx = blockIdx.x * 256 + threadIdx.x;   // 64 blocks -> 16384 threads
    int e  = idx >> 8;                          // 0..63
    int k0 = (idx & 255) << 3;                  // 0..2040, multiple of 8
    const float* wp = W + (size_t)e * DDIM + k0;
    float4 w0 = *(const float4*)wp;
    float4 w1 = *(const float4*)(wp + 4);
    half8v h, l;
    h[0] = (_Float16)w0.x; l[0] = (_Float16)(w0.x - (float)h[0]);
    h[1] = (_Float16)w0.y; l[1] = (_Float16)(w0.y - (float)h[1]);
    h[2] = (_Float16)w0.z; l[2] = (_Float16)(w0.z - (float)h[2]);
    h[3] = (_Float16)w0.w; l[3] = (_Float16)(w0.w - (float)h[3]);
    h[4] = (_Float16)w1.x; l[4] = (_Float16)(w1.x - (float)h[4]);
    h[5] = (_Float16)w1.y; l[5] = (_Float16)(w1.y - (float)h[5]);
    h[6] = (_Float16)w1.z; l[6] = (_Float16)(w1.z - (float)h[6]);
    h[7] = (_Float16)w1.w; l[7] = (_Float16)(w1.w - (float)h[7]);
    int S = k0 >> 5, nb = e >> 4, nl = e & 15, q = (k0 >> 3) & 3;
    size_t off = (size_t)S * 2048 + nb * 512 + q * 128 + nl * 8;
    *(half8v*)&Wh[off] = h;
    *(half8v*)&Wl[off] = l;
    if (idx < 128) accg[idx] = 0.0f;
}

__global__ __launch_bounds__(256, 4) void router_kernel(
    const float* __restrict__ x, const _Float16* __restrict__ Wh,
    const _Float16* __restrict__ Wl, float* __restrict__ accg,
    float* __restrict__ out)
{
    // x chunk: [16 rows][1 KB], 16B granules XOR-swizzled by ((row&7)<<4)
    __shared__ __align__(16) float Xs[2][4096];      // 32 KB, double-buffered
    __shared__ float lgt[TM][NEXP + 1];              // 4.2 KB
    __shared__ float cnt[NEXP];

    const int tid  = threadIdx.x;
    const int lane = tid & 63;
    const int wv   = __builtin_amdgcn_readfirstlane(tid >> 6);  // expert block 0..3
    const int m0   = blockIdx.x * TM;

    if (tid < NEXP) cnt[tid] = 0.0f;

    // ---- staging: round r (0..3), wave wv stages row r*4+wv: 1 KB contiguous.
    // LDS linear dest (floats): r*1024 + wv*256 (+ lane*16B implicit).
    // Global source per lane: byte (lane*16) ^ ((row&7)<<4) within the row
    // chunk (inverse of the read-side swizzle; bijective within 1 KB).
    const float* xrow0 = x + (size_t)(m0 +  0 + wv) * DDIM + ((((lane * 16) ^ (((     wv) & 7) << 4))) >> 2);
    const float* xrow1 = x + (size_t)(m0 +  4 + wv) * DDIM + ((((lane * 16) ^ ((( 4 + wv) & 7) << 4))) >> 2);
    const float* xrow2 = x + (size_t)(m0 +  8 + wv) * DDIM + ((((lane * 16) ^ ((( 8 + wv) & 7) << 4))) >> 2);
    const float* xrow3 = x + (size_t)(m0 + 12 + wv) * DDIM + ((((lane * 16) ^ (((12 + wv) & 7) << 4))) >> 2);

    // W-frag pointers for this wave's 16 experts (frag-linear, L2-hot)
    const _Float16* whp = Wh + wv * 512 + lane * 8;
    const _Float16* wlp = Wl + wv * 512 + lane * 8;

    // ---- compute-side read constants ----
    const int row = lane & 15;
    const int swz = (row & 7) << 4;          // byte swizzle
    const int kb0 = (lane >> 4) * 32;        // byte offset of j=0..3 granule

    f32x4 acc = {0.f, 0.f, 0.f, 0.f};

    // ---- prologue: stage chunk 0 -> buf 0 ----
    stage16(xrow0, &Xs[0][0 * 1024 + wv * 256]);
    stage16(xrow1, &Xs[0][1 * 1024 + wv * 256]);
    stage16(xrow2, &Xs[0][2 * 1024 + wv * 256]);
    stage16(xrow3, &Xs[0][3 * 1024 + wv * 256]);
    __syncthreads();

    for (int c = 0; c < NCH; ++c) {
        const int b  = c & 1;
        const int cn = (c + 1) & (NCH - 1);      // wrap re-stage harmless
        // stage chunk c+1 -> buf b^1 (issue-early; consumed after full chunk)
        stage16(xrow0 + cn * KCH, &Xs[b ^ 1][0 * 1024 + wv * 256]);
        stage16(xrow1 + cn * KCH, &Xs[b ^ 1][1 * 1024 + wv * 256]);
        stage16(xrow2 + cn * KCH, &Xs[b ^ 1][2 * 1024 + wv * 256]);
        stage16(xrow3 + cn * KCH, &Xs[b ^ 1][3 * 1024 + wv * 256]);

        const char* xb = (const char*)&Xs[b][0];
        #pragma unroll
        for (int s = 0; s < SPC; ++s) {
            const int Sg = c * SPC + s;          // global K32 step 0..63
            const float4 xa = *(const float4*)(xb + row * 1024 + ((s * 128 + kb0) ^ swz));
            const float4 xc = *(const float4*)(xb + row * 1024 + ((s * 128 + kb0 + 16) ^ swz));
            half8v ah, al;
            ah[0]=(_Float16)xa.x; al[0]=(_Float16)(xa.x-(float)ah[0]);
            ah[1]=(_Float16)xa.y; al[1]=(_Float16)(xa.y-(float)ah[1]);
            ah[2]=(_Float16)xa.z; al[2]=(_Float16)(xa.z-(float)ah[2]);
            ah[3]=(_Float16)xa.w; al[3]=(_Float16)(xa.w-(float)ah[3]);
            ah[4]=(_Float16)xc.x; al[4]=(_Float16)(xc.x-(float)ah[4]);
            ah[5]=(_Float16)xc.y; al[5]=(_Float16)(xc.y-(float)ah[5]);
            ah[6]=(_Float16)xc.z; al[6]=(_Float16)(xc.z-(float)ah[6]);
            ah[7]=(_Float16)xc.w; al[7]=(_Float16)(xc.w-(float)ah[7]);
            const half8v bh = *(const half8v*)(whp + (size_t)Sg * 2048);
            const half8v bl = *(const half8v*)(wlp + (size_t)Sg * 2048);
            acc = MFMA16(al, bh, acc);
            acc = MFMA16(ah, bl, acc);
            acc = MFMA16(ah, bh, acc);
        }
        // single barrier per chunk: drains the 4 stage-writes (issued ~2600
        // cycles ago -> no stall) and flips buffers.
        __syncthreads();
    }

    // ---- C layout: row m=(lane>>4)*4+r, col n=lane&15 (m89/r5-verified) ----
    {
        const int q  = lane >> 4;
        const int nl = lane & 15;
        #pragma unroll
        for (int r = 0; r < 4; ++r)
            lgt[q * 4 + r][wv * 16 + nl] = acc[r];
    }
    __syncthreads();

    // ---- softmax + top-2: 8 threads per token (16 tok x 8 = 128 thr) ----
    if (tid < 128) {
        const int m = tid >> 3;
        const int j = tid & 7;
        float l[8];
        #pragma unroll
        for (int i = 0; i < 8; ++i) l[i] = lgt[m][j * 8 + i];

        float mx = l[0];
        #pragma unroll
        for (int i = 1; i < 8; ++i) mx = fmaxf(mx, l[i]);
        #pragma unroll
        for (int off = 1; off < 8; off <<= 1) mx = fmaxf(mx, __shfl_xor(mx, off, 8));

        float ev[8];
        float zs = 0.f;
        float v1 = -INFINITY, v2 = -INFINITY;
        int i1 = 0, i2 = 0;
        #pragma unroll
        for (int i = 0; i < 8; ++i) {
            ev[i] = __expf(l[i] - mx);
            zs += ev[i];
            int e = j * 8 + i;
            if (l[i] > v1)      { v2 = v1; i2 = i1; v1 = l[i]; i1 = e; }
            else if (l[i] > v2) { v2 = l[i]; i2 = e; }
        }
        #pragma unroll
        for (int off = 1; off < 8; off <<= 1) zs += __shfl_xor(zs, off, 8);

        // merge top-2 across 8 lanes (value desc, index asc on ties = lax.top_k)
        #pragma unroll
        for (int off = 1; off < 8; off <<= 1) {
            float ov1 = __shfl_xor(v1, off, 8);
            int   oi1 = __shfl_xor(i1, off, 8);
            float ov2 = __shfl_xor(v2, off, 8);
            int   oi2 = __shfl_xor(i2, off, 8);
            bool afirst = (v1 > ov1) || (v1 == ov1 && i1 < oi1);
            if (afirst) {
                bool t = (v2 > ov1) || (v2 == ov1 && i2 < oi1);
                v2 = t ? v2 : ov1;
                i2 = t ? i2 : oi1;
            } else {
                bool t = (ov2 > v1) || (ov2 == v1 && oi2 < i1);
                v2 = t ? ov2 : v1;
                i2 = t ? oi2 : i1;
                v1 = ov1;
                i1 = oi1;
            }
        }

        const float invz = 1.0f / zs;
        if (j == 0) {
            float p1 = invz;                      // v1 == mx exactly
            float p2 = __expf(v2 - mx) * invz;
            float sden = p1 + p2 + 1e-9f;
            int tok = m0 + m;
            out[tok * 2 + 0] = (float)i1;
            out[tok * 2 + 1] = (float)i2;
            out[32768 + tok * 2 + 0] = p1 / sden;
            out[32768 + tok * 2 + 1] = p2 / sden;
            atomicAdd(&cnt[i1], 1.0f);
            atomicAdd(&cnt[i2], 1.0f);
        }

        // probs writeback (own slots only)
        #pragma unroll
        for (int i = 0; i < 8; ++i) lgt[m][j * 8 + i] = ev[i] * invz;
    }
    __syncthreads();

    // global accumulators (accg zeroed by prep each launch)
    if (tid < NEXP) {
        atomicAdd(&accg[tid], cnt[tid]);
    } else if (tid < 128) {
        int e = tid - 64;
        float s = 0.f;
        #pragma unroll
        for (int t = 0; t < TM; ++t) s += lgt[t][e];
        atomicAdd(&accg[64 + e], s);
    }
}

__global__ void finalize_kernel(const float* __restrict__ accg,
                                float* __restrict__ out)
{
    int t = threadIdx.x;   // 64 threads
    float c = accg[t];
    float p = accg[64 + t];
    float term = (c / (float)(NTOK * 2)) * (p / (float)NTOK);
    #pragma unroll
    for (int off = 1; off < 64; off <<= 1) term += __shfl_xor(term, off, 64);
    if (t == 0) out[65536] = 0.01f * (float)NEXP * term;
}

extern "C" void kernel_launch(void* const* d_in, const int* in_sizes, int n_in,
                              void* d_out, int out_size, void* d_ws, size_t ws_size,
                              hipStream_t stream) {
    const float* x = (const float*)d_in[0];   // [4,4096,2048]
    const float* W = (const float*)d_in[1];   // [64,2048]
    float* out  = (float*)d_out;              // 65537 floats
    float* accg = (float*)d_ws;               // 128 floats
    _Float16* Wh = (_Float16*)(accg + 128);   // 131072 halfs (256 KB)
    _Float16* Wl = Wh + (size_t)DDIM * NEXP;  // 131072 halfs (256 KB)

    prep_kernel<<<64, 256, 0, stream>>>(W, Wh, Wl, accg);
    router_kernel<<<NBLK, 256, 0, stream>>>(x, Wh, Wl, accg, out);
    finalize_kernel<<<1, 64, 0, stream>>>(accg, out);
}

// Round 7
// 207.250 us; speedup vs baseline: 1.1251x; 1.1251x over previous
//
#include <hip/hip_runtime.h>
#include <math.h>

// TopKRouter: x[16384,2048] fp32, W[64,2048] fp32
// out: [0..32767] top2 indices (as float), [32768..65535] gates, [65536] aux
// Split-fp16 MFMA (3-term: xh*wh + xh*wl + xl*wh).
// R7: VMEM-instruction reduction. Across R2/R3/R5/R6 the router was invariant
// at 70-91us with ~2560 VMEM wave-instrs/CU (~85cyc/instr) -- and an L3-hot
// replay pass (FETCH~0) ran the SAME duration => bound by vector-memory
// instruction issue/processing, not DRAM. W re-fetch per 16-token block was
// 80% of the instructions. TMB=64 (4 M-tiles/wave, 1 block/CU): W instrs/CU
// 2048->512, total ~2560->~1030. Machinery: R2's proven same-phase LDS
// staging + reg x-ring (depth2, static names) + reg W-ring (dist 2, static)
// + frag-linear XOR-swizzled LDS (b128 granule writes) + lgkm-only barriers.
#define NTOK 16384
#define DDIM 2048
#define NEXP 64
#define TMB  64                 // tokens per block (4 MFMA M-tiles)
#define NBLK (NTOK / TMB)       // 256 blocks -> 1 block/CU
#define NCH  32                 // K chunks of 64
#define NS   64                 // K32 MFMA steps total

typedef _Float16 half8v __attribute__((ext_vector_type(8)));
typedef float    f32x4  __attribute__((ext_vector_type(4)));

#define MFMA16(a, b, c) __builtin_amdgcn_mfma_f32_16x16x32_f16((a), (b), (c), 0, 0, 0)

// W prep: fp32 -> (wh, wl) fp16 in MFMA-B fragment-linear layout (r5-verified):
// element (e,k): S=k>>5, nb=e>>4, nl=e&15, q=(k>>3)&3, j=k&7
// off = S*2048 + nb*512 + q*128 + nl*8 + j
__global__ __launch_bounds__(256) void prep_kernel(const float* __restrict__ W,
                                                   _Float16* __restrict__ Wh,
                                                   _Float16* __restrict__ Wl,
                                                   float* __restrict__ accg) {
    int idx = blockIdx.x * 256 + threadIdx.x;   // 64 blocks -> 16384 threads
    int e  = idx >> 8;                          // 0..63
    int k0 = (idx & 255) << 3;                  // 0..2040, multiple of 8
    const float* wp = W + (size_t)e * DDIM + k0;
    float4 w0 = *(const float4*)wp;
    float4 w1 = *(const float4*)(wp + 4);
    half8v h, l;
    h[0] = (_Float16)w0.x; l[0] = (_Float16)(w0.x - (float)h[0]);
    h[1] = (_Float16)w0.y; l[1] = (_Float16)(w0.y - (float)h[1]);
    h[2] = (_Float16)w0.z; l[2] = (_Float16)(w0.z - (float)h[2]);
    h[3] = (_Float16)w0.w; l[3] = (_Float16)(w0.w - (float)h[3]);
    h[4] = (_Float16)w1.x; l[4] = (_Float16)(w1.x - (float)h[4]);
    h[5] = (_Float16)w1.y; l[5] = (_Float16)(w1.y - (float)h[5]);
    h[6] = (_Float16)w1.z; l[6] = (_Float16)(w1.z - (float)h[6]);
    h[7] = (_Float16)w1.w; l[7] = (_Float16)(w1.w - (float)h[7]);
    int S = k0 >> 5, nb = e >> 4, nl = e & 15, q = (k0 >> 3) & 3;
    size_t off = (size_t)S * 2048 + nb * 512 + q * 128 + nl * 8;
    *(half8v*)&Wh[off] = h;
    *(half8v*)&Wl[off] = l;
    if (idx < 128) accg[idx] = 0.0f;
}

// convert 8 consecutive fp32 (one full 16B LDS granule) -> h,l half8v
__device__ __forceinline__ void cvt8(float4 a, float4 b, half8v& h, half8v& l) {
    h[0]=(_Float16)a.x; l[0]=(_Float16)(a.x-(float)h[0]);
    h[1]=(_Float16)a.y; l[1]=(_Float16)(a.y-(float)h[1]);
    h[2]=(_Float16)a.z; l[2]=(_Float16)(a.z-(float)h[2]);
    h[3]=(_Float16)a.w; l[3]=(_Float16)(a.w-(float)h[3]);
    h[4]=(_Float16)b.x; l[4]=(_Float16)(b.x-(float)h[4]);
    h[5]=(_Float16)b.y; l[5]=(_Float16)(b.y-(float)h[5]);
    h[6]=(_Float16)b.z; l[6]=(_Float16)(b.z-(float)h[6]);
    h[7]=(_Float16)b.w; l[7]=(_Float16)(b.w-(float)h[7]);
}

__global__ __launch_bounds__(256, 1) void router_kernel(
    const float* __restrict__ x, const _Float16* __restrict__ Wh,
    const _Float16* __restrict__ Wl, float* __restrict__ accg,
    float* __restrict__ out)
{
    // A frag-linear fp16, XOR-swizzled 16B granules, double-buffered:
    // [buf][tile(4)][granule g=S*64+q*16+tok, swz][8 halfs]
    __shared__ __align__(16) _Float16 Ah[2][4096];   // 16 KB
    __shared__ __align__(16) _Float16 Al[2][4096];   // 16 KB
    __shared__ float lgt[TMB][NEXP + 1];             // 16.6 KB
    __shared__ float cnt[NEXP];

    const int tid  = threadIdx.x;
    const int lane = tid & 63;
    const int wv   = __builtin_amdgcn_readfirstlane(tid >> 6);  // expert block 0..3
    const int m0   = blockIdx.x * TMB;

    if (tid < NEXP) cnt[tid] = 0.0f;

    // ---- staging map: thread t -> row r=t>>2 (0..63), cols c0..c0+15 ----
    const int r    = tid >> 2;
    const int c0   = (tid & 3) * 16;
    const int tile = r >> 4, tok = r & 15;
    // two full granules per thread: kk0=c0, kk1=c0+8
    const int S0 = c0 >> 5,       q0 = (c0 >> 3) & 3;
    const int S1 = (c0+8) >> 5,   q1 = ((c0+8) >> 3) & 3;
    const int g0 = S0*64 + q0*16 + tok,  g1 = S1*64 + q1*16 + tok;
    const int off0 = tile*1024 + (g0 ^ ((g0>>4)&7)) * 8;
    const int off1 = tile*1024 + (g1 ^ ((g1>>4)&7)) * 8;

    const float* gx = x + (size_t)(m0 + r) * DDIM + c0;

    // ---- read-side swizzled offsets (same per tile, +tile*1024) ----
    const int gr1 = 64 + lane;
    const int rd0 = (lane ^ ((lane>>4)&7)) * 8;
    const int rd1 = (gr1 ^ ((gr1>>4)&7)) * 8;

    // W-frag pointers for this wave's 16 experts (frag-linear, L2-hot)
    const _Float16* whp = Wh + wv * 512 + lane * 8;
    const _Float16* wlp = Wl + wv * 512 + lane * 8;

    f32x4 acc0 = {0.f,0.f,0.f,0.f}, acc1 = {0.f,0.f,0.f,0.f};
    f32x4 acc2 = {0.f,0.f,0.f,0.f}, acc3 = {0.f,0.f,0.f,0.f};

    // ---- prologue: x ring depth 2 (chunks 0,1), W ring 4 slots (steps 0..3)
    float4 xa0 = *(const float4*)(gx +  0), xa1 = *(const float4*)(gx +  4);
    float4 xa2 = *(const float4*)(gx +  8), xa3 = *(const float4*)(gx + 12);
    float4 xb0 = *(const float4*)(gx + 64), xb1 = *(const float4*)(gx + 68);
    float4 xb2 = *(const float4*)(gx + 72), xb3 = *(const float4*)(gx + 76);
    half8v wh0 = *(const half8v*)(whp);
    half8v wh1 = *(const half8v*)(whp + 2048);
    half8v wh2 = *(const half8v*)(whp + 4096);
    half8v wh3 = *(const half8v*)(whp + 6144);
    half8v wl0 = *(const half8v*)(wlp);
    half8v wl1 = *(const half8v*)(wlp + 2048);
    half8v wl2 = *(const half8v*)(wlp + 4096);
    half8v wl3 = *(const half8v*)(wlp + 6144);

    // One chunk: stage 16 floats (2 granules) as h/l b128 -> LDS[P];
    // prefetch x(ch+2) into the same named regs; lgkm-only barrier;
    // 2 K32 steps x {8 ds_read_b128 (4 tiles), W prefetch (+4), 12 MFMA}.
#define CHUNK(ch, X0, X1, X2, X3, P, WHA, WLA, WHB, WLB)                    \
    {                                                                        \
        half8v h_, l_;                                                       \
        cvt8(X0, X1, h_, l_);                                                \
        *(half8v*)&Ah[P][off0] = h_;  *(half8v*)&Al[P][off0] = l_;           \
        cvt8(X2, X3, h_, l_);                                                \
        *(half8v*)&Ah[P][off1] = h_;  *(half8v*)&Al[P][off1] = l_;           \
        const int cf = ((ch) + 2 < NCH) ? (ch) + 2 : 0;                      \
        X0 = *(const float4*)(gx + cf * 64 +  0);                            \
        X1 = *(const float4*)(gx + cf * 64 +  4);                            \
        X2 = *(const float4*)(gx + cf * 64 +  8);                            \
        X3 = *(const float4*)(gx + cf * 64 + 12);                            \
        asm volatile("s_waitcnt lgkmcnt(0)" ::: "memory");                   \
        __builtin_amdgcn_s_barrier();                                        \
        {   /* step Sg = 2*ch */                                             \
            half8v a0h = *(const half8v*)&Ah[P][   0 + rd0];                 \
            half8v a0l = *(const half8v*)&Al[P][   0 + rd0];                 \
            half8v a1h = *(const half8v*)&Ah[P][1024 + rd0];                 \
            half8v a1l = *(const half8v*)&Al[P][1024 + rd0];                 \
            half8v a2h = *(const half8v*)&Ah[P][2048 + rd0];                 \
            half8v a2l = *(const half8v*)&Al[P][2048 + rd0];                 \
            half8v a3h = *(const half8v*)&Ah[P][3072 + rd0];                 \
            half8v a3l = *(const half8v*)&Al[P][3072 + rd0];                 \
            half8v bh = WHA, bl = WLA;                                       \
            const int SgN = (2 * (ch) + 4) & (NS - 1);                       \
            WHA = *(const half8v*)(whp + (size_t)SgN * 2048);                \
            WLA = *(const half8v*)(wlp + (size_t)SgN * 2048);                \
            acc0 = MFMA16(a0l, bh, acc0);                                    \
            acc0 = MFMA16(a0h, bl, acc0);                                    \
            acc0 = MFMA16(a0h, bh, acc0);                                    \
            acc1 = MFMA16(a1l, bh, acc1);                                    \
            acc1 = MFMA16(a1h, bl, acc1);                                    \
            acc1 = MFMA16(a1h, bh, acc1);                                    \
            acc2 = MFMA16(a2l, bh, acc2);                                    \
            acc2 = MFMA16(a2h, bl, acc2);                                    \
            acc2 = MFMA16(a2h, bh, acc2);                                    \
            acc3 = MFMA16(a3l, bh, acc3);                                    \
            acc3 = MFMA16(a3h, bl, acc3);                                    \
            acc3 = MFMA16(a3h, bh, acc3);                                    \
        }                                                                    \
        {   /* step Sg = 2*ch+1 */                                           \
            half8v a0h = *(const half8v*)&Ah[P][   0 + rd1];                 \
            half8v a0l = *(const half8v*)&Al[P][   0 + rd1];                 \
            half8v a1h = *(const half8v*)&Ah[P][1024 + rd1];                 \
            half8v a1l = *(const half8v*)&Al[P][1024 + rd1];                 \
            half8v a2h = *(const half8v*)&Ah[P][2048 + rd1];                 \
            half8v a2l = *(const half8v*)&Al[P][2048 + rd1];                 \
            half8v a3h = *(const half8v*)&Ah[P][3072 + rd1];                 \
            half8v a3l = *(const half8v*)&Al[P][3072 + rd1];                 \
            half8v bh = WHB, bl = WLB;                                       \
            const int SgN = (2 * (ch) + 5) & (NS - 1);                       \
            WHB = *(const half8v*)(whp + (size_t)SgN * 2048);                \
            WLB = *(const half8v*)(wlp + (size_t)SgN * 2048);                \
            acc0 = MFMA16(a0l, bh, acc0);                                    \
            acc0 = MFMA16(a0h, bl, acc0);                                    \
            acc0 = MFMA16(a0h, bh, acc0);                                    \
            acc1 = MFMA16(a1l, bh, acc1);                                    \
            acc1 = MFMA16(a1h, bl, acc1);                                    \
            acc1 = MFMA16(a1h, bh, acc1);                                    \
            acc2 = MFMA16(a2l, bh, acc2);                                    \
            acc2 = MFMA16(a2h, bl, acc2);                                    \
            acc2 = MFMA16(a2h, bh, acc2);                                    \
            acc3 = MFMA16(a3l, bh, acc3);                                    \
            acc3 = MFMA16(a3h, bl, acc3);                                    \
            acc3 = MFMA16(a3h, bh, acc3);                                    \
        }                                                                    \
        /* dbuf parity barrier: next chunk writes buf P^1 while others read */\
        asm volatile("s_waitcnt lgkmcnt(0)" ::: "memory");                   \
        __builtin_amdgcn_s_barrier();                                        \
    }

    for (int cb = 0; cb < NCH; cb += 2) {
        CHUNK(cb + 0, xa0, xa1, xa2, xa3, 0, wh0, wl0, wh1, wl1);
        CHUNK(cb + 1, xb0, xb1, xb2, xb3, 1, wh2, wl2, wh3, wl3);
    }
#undef CHUNK

    // ---- C layout: row m=(lane>>4)*4+r, col n=lane&15 (m89/r5-verified) ----
    {
        const int qr = lane >> 4;
        const int nl = lane & 15;
        #pragma unroll
        for (int rr = 0; rr < 4; ++rr) {
            const int mm = qr * 4 + rr;
            lgt[ 0 + mm][wv * 16 + nl] = acc0[rr];
            lgt[16 + mm][wv * 16 + nl] = acc1[rr];
            lgt[32 + mm][wv * 16 + nl] = acc2[rr];
            lgt[48 + mm][wv * 16 + nl] = acc3[rr];
        }
    }
    __syncthreads();

    // ---- softmax + top-2: 8 threads/token, 2 passes of 32 tokens ----
    for (int pass = 0; pass < 2; ++pass) {
        const int m = pass * 32 + (tid >> 3);
        const int j = tid & 7;
        float l[8];
        #pragma unroll
        for (int i = 0; i < 8; ++i) l[i] = lgt[m][j * 8 + i];

        float mx = l[0];
        #pragma unroll
        for (int i = 1; i < 8; ++i) mx = fmaxf(mx, l[i]);
        #pragma unroll
        for (int off = 1; off < 8; off <<= 1) mx = fmaxf(mx, __shfl_xor(mx, off, 8));

        float ev[8];
        float zs = 0.f;
        float v1 = -INFINITY, v2 = -INFINITY;
        int i1 = 0, i2 = 0;
        #pragma unroll
        for (int i = 0; i < 8; ++i) {
            ev[i] = __expf(l[i] - mx);
            zs += ev[i];
            int e = j * 8 + i;
            if (l[i] > v1)      { v2 = v1; i2 = i1; v1 = l[i]; i1 = e; }
            else if (l[i] > v2) { v2 = l[i]; i2 = e; }
        }
        #pragma unroll
        for (int off = 1; off < 8; off <<= 1) zs += __shfl_xor(zs, off, 8);

        // merge top-2 across 8 lanes (value desc, index asc on ties = lax.top_k)
        #pragma unroll
        for (int off = 1; off < 8; off <<= 1) {
            float ov1 = __shfl_xor(v1, off, 8);
            int   oi1 = __shfl_xor(i1, off, 8);
            float ov2 = __shfl_xor(v2, off, 8);
            int   oi2 = __shfl_xor(i2, off, 8);
            bool afirst = (v1 > ov1) || (v1 == ov1 && i1 < oi1);
            if (afirst) {
                bool t = (v2 > ov1) || (v2 == ov1 && i2 < oi1);
                v2 = t ? v2 : ov1;
                i2 = t ? i2 : oi1;
            } else {
                bool t = (ov2 > v1) || (ov2 == v1 && oi2 < i1);
                v2 = t ? ov2 : v1;
                i2 = t ? oi2 : i1;
                v1 = ov1;
                i1 = oi1;
            }
        }

        const float invz = 1.0f / zs;
        if (j == 0) {
            float p1 = invz;                      // v1 == mx exactly
            float p2 = __expf(v2 - mx) * invz;
            float sden = p1 + p2 + 1e-9f;
            int tokg = m0 + m;
            out[tokg * 2 + 0] = (float)i1;
            out[tokg * 2 + 1] = (float)i2;
            out[32768 + tokg * 2 + 0] = p1 / sden;
            out[32768 + tokg * 2 + 1] = p2 / sden;
            atomicAdd(&cnt[i1], 1.0f);
            atomicAdd(&cnt[i2], 1.0f);
        }

        // probs writeback (own slots only)
        #pragma unroll
        for (int i = 0; i < 8; ++i) lgt[m][j * 8 + i] = ev[i] * invz;
    }
    __syncthreads();

    // global accumulators (accg zeroed by prep each launch)
    if (tid < NEXP) {
        atomicAdd(&accg[tid], cnt[tid]);
    } else if (tid < 128) {
        int e = tid - 64;
        float s = 0.f;
        #pragma unroll
        for (int t = 0; t < TMB; ++t) s += lgt[t][e];
        atomicAdd(&accg[64 + e], s);
    }
}

__global__ void finalize_kernel(const float* __restrict__ accg,
                                float* __restrict__ out)
{
    int t = threadIdx.x;   // 64 threads
    float c = accg[t];
    float p = accg[64 + t];
    float term = (c / (float)(NTOK * 2)) * (p / (float)NTOK);
    #pragma unroll
    for (int off = 1; off < 64; off <<= 1) term += __shfl_xor(term, off, 64);
    if (t == 0) out[65536] = 0.01f * (float)NEXP * term;
}

extern "C" void kernel_launch(void* const* d_in, const int* in_sizes, int n_in,
                              void* d_out, int out_size, void* d_ws, size_t ws_size,
                              hipStream_t stream) {
    const float* x = (const float*)d_in[0];   // [4,4096,2048]
    const float* W = (const float*)d_in[1];   // [64,2048]
    float* out  = (float*)d_out;              // 65537 floats
    float* accg = (float*)d_ws;               // 128 floats
    _Float16* Wh = (_Float16*)(accg + 128);   // 131072 halfs (256 KB)
    _Float16* Wl = Wh + (size_t)DDIM * NEXP;  // 131072 halfs (256 KB)

    prep_kernel<<<64, 256, 0, stream>>>(W, Wh, Wl, accg);
    router_kernel<<<NBLK, 256, 0, stream>>>(x, Wh, Wl, accg, out);
    finalize_kernel<<<1, 64, 0, stream>>>(accg, out);
}